// Round 3
// baseline (1949.620 us; speedup 1.0000x reference)
//
#include <hip/hip_runtime.h>
#include <hip/hip_bf16.h>
#include <stdint.h>

// ---------------------------------------------------------------------------
// TransformerDecoderModel on MI355X (gfx950).
// bf16 MFMA GEMMs (f32 accumulate), f32 residual/LN/softmax.
// ---------------------------------------------------------------------------

typedef __bf16 bf16;
typedef __bf16 b16x8 __attribute__((ext_vector_type(8)));  // storage/stores
typedef short  s16x8 __attribute__((ext_vector_type(8)));  // MFMA A/B frags
typedef float  f32x4 __attribute__((ext_vector_type(4)));

#define D_      1024
#define H_      16
#define DH_     64
#define S_      1024
#define B_      2
#define L_      4
#define DFF_    4096
#define V_      32000
#define TOK_    (B_ * S_)
#define MAXLEN_ 1024

__device__ __forceinline__ void gload_lds16(const void* g, void* l) {
  // async global->LDS, 16B/lane; LDS dest = wave-uniform base + lane*16
  __builtin_amdgcn_global_load_lds((__attribute__((address_space(1))) void*)(g),
                                   (__attribute__((address_space(3))) void*)(l),
                                   16, 0, 0);
}

__device__ __forceinline__ void store_b8(bf16* p, float4 a, float4 b) {
  b16x8 o;
  o[0] = (bf16)a.x; o[1] = (bf16)a.y; o[2] = (bf16)a.z; o[3] = (bf16)a.w;
  o[4] = (bf16)b.x; o[5] = (bf16)b.y; o[6] = (bf16)b.z; o[7] = (bf16)b.w;
  *(b16x8*)p = o;
}

// ---------------------------------------------------------------------------
// f32 -> bf16 bulk convert (8 elems/thread, vectorized); exact-size grids
// ---------------------------------------------------------------------------
__global__ __launch_bounds__(256) void cvt_bf16(const float* __restrict__ in,
                                                bf16* __restrict__ out, int n) {
  const int i = (blockIdx.x * 256 + threadIdx.x) * 8;
  if (i + 8 > n) return;
  float4 a = *(const float4*)&in[i];
  float4 b = *(const float4*)&in[i + 4];
  store_b8(&out[i], a, b);
}

// ---------------------------------------------------------------------------
// Per-layer small conversions, one launch:
//  blocks [0,2048):   Wq/Wk/Wv -> packed wqkv rows {0..3071}, Wo -> wo
//  blocks [2048,2112): rel -> relb (2047*64 elems)
//  blocks [2112,2124): pack bq|bk|bv -> bqkv[3072] (f32)
// ---------------------------------------------------------------------------
__global__ __launch_bounds__(256) void cvt_small(
    const float* __restrict__ Wq, const float* __restrict__ Wk,
    const float* __restrict__ Wv, const float* __restrict__ Wo,
    const float* __restrict__ bq, const float* __restrict__ bk,
    const float* __restrict__ bv, const float* __restrict__ rel,
    bf16* __restrict__ wqkv, bf16* __restrict__ wo,
    float* __restrict__ bqkv, bf16* __restrict__ relb) {
  const int blk = blockIdx.x;
  if (blk < 2048) {
    const int id = blk >> 9;                              // 0..3
    const int off = (blk & 511) * 2048 + threadIdx.x * 8; // within 1M elems
    const float* src = (id == 0) ? Wq : (id == 1) ? Wk : (id == 2) ? Wv : Wo;
    bf16* dst = (id < 3) ? (wqkv + (size_t)id * D_ * D_) : wo;
    float4 a = *(const float4*)&src[off];
    float4 b = *(const float4*)&src[off + 4];
    store_b8(&dst[off], a, b);
  } else if (blk < 2112) {
    const int i = ((blk - 2048) * 256 + threadIdx.x) * 8;
    if (i + 8 > (2 * MAXLEN_ - 1) * DH_) return;
    float4 a = *(const float4*)&rel[i];
    float4 b = *(const float4*)&rel[i + 4];
    store_b8(&relb[i], a, b);
  } else {
    const int i = (blk - 2112) * 256 + threadIdx.x;       // 0..3071
    bqkv[i] = (i < 1024) ? bq[i] : (i < 2048) ? bk[i - 1024] : bv[i - 2048];
  }
}

// ---------------------------------------------------------------------------
// Embedding gather: x = emb[tgt] * sqrt(D) ; writes f32 + bf16 copies
// ---------------------------------------------------------------------------
__global__ __launch_bounds__(256) void embed_k(const int* __restrict__ tgt,
                                               const float* __restrict__ emb,
                                               float* __restrict__ xo,
                                               bf16* __restrict__ xb) {
  const int row = blockIdx.x;
  const int c4  = threadIdx.x * 4;
  const int tok = tgt[row];
  float4 e = *(const float4*)&emb[(long long)tok * D_ + c4];
  e.x *= 32.f; e.y *= 32.f; e.z *= 32.f; e.w *= 32.f;
  *(float4*)&xo[(long long)row * D_ + c4] = e;
  bf16* p = &xb[(long long)row * D_ + c4];
  p[0] = (bf16)e.x; p[1] = (bf16)e.y; p[2] = (bf16)e.z; p[3] = (bf16)e.w;
}

// ---------------------------------------------------------------------------
// Residual + LayerNorm (f32): xo = LN(x + t)*g + be ; also bf16 copy
// ---------------------------------------------------------------------------
__global__ __launch_bounds__(256) void resid_ln(const float* __restrict__ x,
                                                const float* __restrict__ t,
                                                const float* __restrict__ g,
                                                const float* __restrict__ be,
                                                float* __restrict__ xo,
                                                bf16* __restrict__ xb) {
  __shared__ float red[8];
  const int row = blockIdx.x, tid = threadIdx.x;
  const int w = tid >> 6, lane = tid & 63;
  const long long base = (long long)row * D_ + tid * 4;
  float4 xv = *(const float4*)&x[base];
  float4 tv = *(const float4*)&t[base];
  float z0 = xv.x + tv.x, z1 = xv.y + tv.y, z2 = xv.z + tv.z, z3 = xv.w + tv.w;
  float s = z0 + z1 + z2 + z3;
#pragma unroll
  for (int o = 32; o >= 1; o >>= 1) s += __shfl_xor(s, o);
  if (lane == 0) red[w] = s;
  __syncthreads();
  const float mu = (red[0] + red[1] + red[2] + red[3]) * (1.f / D_);
  z0 -= mu; z1 -= mu; z2 -= mu; z3 -= mu;
  float q = z0 * z0 + z1 * z1 + z2 * z2 + z3 * z3;
#pragma unroll
  for (int o = 32; o >= 1; o >>= 1) q += __shfl_xor(q, o);
  if (lane == 0) red[4 + w] = q;
  __syncthreads();
  const float var = (red[4] + red[5] + red[6] + red[7]) * (1.f / D_);
  const float rs = rsqrtf(var + 1e-5f);
  const int c = tid * 4;
  float y0 = z0 * rs * g[c]     + be[c];
  float y1 = z1 * rs * g[c + 1] + be[c + 1];
  float y2 = z2 * rs * g[c + 2] + be[c + 2];
  float y3 = z3 * rs * g[c + 3] + be[c + 3];
  float4 yo = {y0, y1, y2, y3};
  *(float4*)&xo[base] = yo;
  bf16* p = &xb[base];
  p[0] = (bf16)y0; p[1] = (bf16)y1; p[2] = (bf16)y2; p[3] = (bf16)y3;
}

// ---------------------------------------------------------------------------
// GEMM: C[m,n] = sum_k A[m,k]*Bw[n,k]  (B^T form; both row-major, K contig)
// 128x128 tile, BK=64, 4 waves (2x2), mfma 16x16x32 bf16 (m97 structure).
// QKV3 epilogue: packed N=3072 output -> [3][B*H][S][DH], Q third scaled.
// ---------------------------------------------------------------------------
template <bool HAS_BIAS, bool RELU, bool OUT_F32, bool OUT_BF16, bool QKV3>
__global__ __launch_bounds__(256) void gemm_bt(
    const bf16* __restrict__ A, const bf16* __restrict__ Bw,
    const float* __restrict__ bias, float* __restrict__ Cf,
    bf16* __restrict__ Cb, int M, int N, int K, int lda, int ldb,
    long long sA, long long sB, long long sC, float scale) {
  __shared__ alignas(16) bf16 As[128 * 64];
  __shared__ alignas(16) bf16 Bs[128 * 64];
  const int tid = threadIdx.x;
  const int w = tid >> 6, lane = tid & 63;
  const int m0 = blockIdx.x * 128, n0 = blockIdx.y * 128;
  A  += (long long)blockIdx.z * sA;
  Bw += (long long)blockIdx.z * sB;
  const int wr = w >> 1, wc = w & 1;
  const int srow = lane >> 3;        // staging row within 8-row chunk
  const int scol = (lane & 7) * 8;   // staging k element
  const int fr = lane & 15, fg = lane >> 4;

  const f32x4 zero4 = {0.f, 0.f, 0.f, 0.f};
  f32x4 acc[4][4];
#pragma unroll
  for (int m = 0; m < 4; ++m)
#pragma unroll
    for (int n = 0; n < 4; ++n) acc[m][n] = zero4;

  const bf16* Ag[4];
  const bf16* Bg[4];
#pragma unroll
  for (int i = 0; i < 4; ++i) {
    const int c = w * 4 + i;
    Ag[i] = A  + (long long)(m0 + c * 8 + srow) * lda + scol;
    Bg[i] = Bw + (long long)(n0 + c * 8 + srow) * ldb + scol;
  }

  for (int k0 = 0; k0 < K; k0 += 64) {
    __syncthreads();
#pragma unroll
    for (int i = 0; i < 4; ++i) {
      const int c = w * 4 + i;
      gload_lds16(Ag[i] + k0, &As[c * 512]);
      gload_lds16(Bg[i] + k0, &Bs[c * 512]);
    }
    __syncthreads();
#pragma unroll
    for (int ks = 0; ks < 2; ++ks) {
      s16x8 af[4], bfr[4];
#pragma unroll
      for (int m = 0; m < 4; ++m)
        af[m] = *(const s16x8*)&As[(wr * 64 + m * 16 + fr) * 64 + ks * 32 + fg * 8];
#pragma unroll
      for (int n = 0; n < 4; ++n)
        bfr[n] = *(const s16x8*)&Bs[(wc * 64 + n * 16 + fr) * 64 + ks * 32 + fg * 8];
#pragma unroll
      for (int m = 0; m < 4; ++m)
#pragma unroll
        for (int n = 0; n < 4; ++n)
          acc[m][n] = __builtin_amdgcn_mfma_f32_16x16x32_bf16(af[m], bfr[n],
                                                              acc[m][n], 0, 0, 0);
    }
  }

#pragma unroll
  for (int n = 0; n < 4; ++n) {
    const int col = n0 + wc * 64 + n * 16 + fr;
    float bv = 0.f;
    if constexpr (HAS_BIAS) bv = bias[col];
    const float csc = QKV3 ? ((col < 1024) ? 0.125f : 1.0f) : scale;
#pragma unroll
    for (int m = 0; m < 4; ++m) {
      const int rowb = m0 + wr * 64 + m * 16 + fg * 4;
#pragma unroll
      for (int r = 0; r < 4; ++r) {
        float val = (acc[m][n][r] + bv) * csc;
        if constexpr (RELU) val = fmaxf(val, 0.f);
        const int row = rowb + r;
        if constexpr (OUT_F32)
          Cf[(long long)blockIdx.z * sC + (long long)row * N + col] = val;
        if constexpr (OUT_BF16) {
          if constexpr (QKV3) {
            const int which = col >> 10;          // 0=q 1=k 2=v
            const int hh = (col >> 6) & 15, dd = col & 63;
            const int bb = row >> 10, ss = row & 1023;
            Cb[((((long long)which * 32 + bb * 16 + hh) * 1024) + ss) * 64 + dd] =
                (bf16)val;
          } else {
            Cb[(long long)blockIdx.z * sC + (long long)row * N + col] = (bf16)val;
          }
        }
      }
    }
  }
}

// ---------------------------------------------------------------------------
// Flash attention with precomputed rel-bias table QR[bh,i,u] (u = j-i+1023).
// q,k,v in [B*H, S, DH] bf16 (q pre-scaled by 1/8). o out in [B, S, D] bf16.
// grid = (S/64, B*H); 4 waves, each owns 16 q-rows; KV tiles of 64.
// ---------------------------------------------------------------------------
__global__ __launch_bounds__(256) void attn_k(
    const bf16* __restrict__ q, const bf16* __restrict__ k,
    const bf16* __restrict__ v, const bf16* __restrict__ qr,
    const int* __restrict__ tgt, bf16* __restrict__ o) {
  __shared__ alignas(16) bf16 Ks[64 * 72];       // [j][d] padded (+8 bf16)
  __shared__ alignas(16) bf16 Vts[64 * 72];      // [d][j] padded (transposed V)
  __shared__ alignas(16) bf16 Ps[4][16 * 72];    // per-wave P tile [i][j] padded
  __shared__ float padf[64];

  const int qblk = blockIdx.x, bh = blockIdx.y;
  const int b = bh >> 4;
  const int tid = threadIdx.x;
  const int w = tid >> 6, lane = tid & 63;
  const int fr = lane & 15, fg = lane >> 4;
  const int q0 = qblk * 64;
  const int ib = q0 + w * 16;        // wave's q-row base

  const long long qrow = (long long)bh * S_ + (ib + fr);
  const s16x8 qf0 = *(const s16x8*)&q[qrow * DH_ + fg * 8];
  const s16x8 qf1 = *(const s16x8*)&q[qrow * DH_ + 32 + fg * 8];

  const f32x4 zero4 = {0.f, 0.f, 0.f, 0.f};
  f32x4 accO[4];
#pragma unroll
  for (int dt = 0; dt < 4; ++dt) accO[dt] = zero4;
  float mrow[4], lrow[4];
#pragma unroll
  for (int r = 0; r < 4; ++r) { mrow[r] = -1e30f; lrow[r] = 0.f; }

  const int ntile = qblk + 1;        // causal: only j-tiles up to q-block
  for (int jt = 0; jt < ntile; ++jt) {
    const int j0 = jt * 64;
    __syncthreads();
    // stage K [j][d] and V^T [d][j]
#pragma unroll
    for (int rep = 0; rep < 2; ++rep) {
      const int c = tid + rep * 256;
      const int row = c >> 3, ch = c & 7;
      const long long gb = ((long long)bh * S_ + j0 + row) * DH_ + ch * 8;
      b16x8 kv = *(const b16x8*)&k[gb];
      *(b16x8*)&Ks[row * 72 + ch * 8] = kv;
      b16x8 vv = *(const b16x8*)&v[gb];
#pragma unroll
      for (int e = 0; e < 8; ++e) Vts[(ch * 8 + e) * 72 + row] = vv[e];
    }
    if (tid < 64) padf[tid] = (tgt[b * S_ + j0 + tid] == 0) ? 1.f : 0.f;
    __syncthreads();

    // scores: S = Q * K^T  (16 x 64 per wave)
    f32x4 sc[4];
#pragma unroll
    for (int t = 0; t < 4; ++t) {
      f32x4 s = zero4;
      s16x8 k0 = *(const s16x8*)&Ks[(t * 16 + fr) * 72 + fg * 8];
      s16x8 k1 = *(const s16x8*)&Ks[(t * 16 + fr) * 72 + 32 + fg * 8];
      s = __builtin_amdgcn_mfma_f32_16x16x32_bf16(qf0, k0, s, 0, 0, 0);
      s = __builtin_amdgcn_mfma_f32_16x16x32_bf16(qf1, k1, s, 0, 0, 0);
      sc[t] = s;
    }

    // + rel bias gather, causal & pad masking (replace with -1e9, like ref)
#pragma unroll
    for (int t = 0; t < 4; ++t) {
      const int j = j0 + t * 16 + fr;
      const float pd = padf[t * 16 + fr];
#pragma unroll
      for (int r = 0; r < 4; ++r) {
        const int i = ib + fg * 4 + r;
        float sv;
        if (j > i || pd != 0.f)
          sv = -1e9f;
        else
          sv = sc[t][r] +
               (float)qr[((long long)bh * S_ + i) * S_ + (j - i + (MAXLEN_ - 1))];
        sc[t][r] = sv;
      }
    }

    // online softmax update (per q-row; row spans 16 lanes x 4 t)
#pragma unroll
    for (int r = 0; r < 4; ++r) {
      float rm = fmaxf(fmaxf(sc[0][r], sc[1][r]), fmaxf(sc[2][r], sc[3][r]));
#pragma unroll
      for (int off = 1; off < 16; off <<= 1) rm = fmaxf(rm, __shfl_xor(rm, off));
      const float mnew = fmaxf(mrow[r], rm);
      const float f = __expf(mrow[r] - mnew);
      mrow[r] = mnew;
      lrow[r] *= f;
#pragma unroll
      for (int dt = 0; dt < 4; ++dt) accO[dt][r] *= f;
      float ps = 0.f;
#pragma unroll
      for (int t = 0; t < 4; ++t) {
        const float p = __expf(sc[t][r] - mnew);
        ps += p;
        Ps[w][(fg * 4 + r) * 72 + t * 16 + fr] = (bf16)p;
      }
#pragma unroll
      for (int off = 1; off < 16; off <<= 1) ps += __shfl_xor(ps, off);
      lrow[r] += ps;
    }

    // O += P * V   (wave-private P in LDS; same-wave ds ordering via compiler)
#pragma unroll
    for (int dt = 0; dt < 4; ++dt) {
#pragma unroll
      for (int ks = 0; ks < 2; ++ks) {
        s16x8 pa = *(const s16x8*)&Ps[w][fr * 72 + ks * 32 + fg * 8];
        s16x8 vbf = *(const s16x8*)&Vts[(dt * 16 + fr) * 72 + ks * 32 + fg * 8];
        accO[dt] = __builtin_amdgcn_mfma_f32_16x16x32_bf16(pa, vbf, accO[dt], 0, 0, 0);
      }
    }
  }

#pragma unroll
  for (int r = 0; r < 4; ++r) lrow[r] = 1.f / lrow[r];
  const int h = bh & 15;
#pragma unroll
  for (int dt = 0; dt < 4; ++dt) {
#pragma unroll
    for (int r = 0; r < 4; ++r) {
      const int i = ib + fg * 4 + r;
      o[((long long)b * S_ + i) * D_ + h * DH_ + dt * 16 + fr] =
          (bf16)(accO[dt][r] * lrow[r]);
    }
  }
}

// ---------------------------------------------------------------------------
// Launcher
// ---------------------------------------------------------------------------
extern "C" void kernel_launch(void* const* d_in, const int* in_sizes, int n_in,
                              void* d_out, int out_size, void* d_ws,
                              size_t ws_size, hipStream_t stream) {
  (void)in_sizes; (void)n_in; (void)out_size;
  const int*   tgt = (const int*)d_in[0];
  const float* emb = (const float*)d_in[1];
  const float* Wq  = (const float*)d_in[2];
  const float* bq  = (const float*)d_in[3];
  const float* Wk  = (const float*)d_in[4];
  const float* bk  = (const float*)d_in[5];
  const float* Wv  = (const float*)d_in[6];
  const float* bv  = (const float*)d_in[7];
  const float* Wo  = (const float*)d_in[8];
  const float* bo  = (const float*)d_in[9];
  const float* rel = (const float*)d_in[10];
  const float* W1  = (const float*)d_in[11];
  const float* b1  = (const float*)d_in[12];
  const float* W2  = (const float*)d_in[13];
  const float* b2  = (const float*)d_in[14];
  const float* g1  = (const float*)d_in[15];
  const float* be1 = (const float*)d_in[16];
  const float* g2  = (const float*)d_in[17];
  const float* be2 = (const float*)d_in[18];
  const float* Wf  = (const float*)d_in[19];
  const float* bfv = (const float*)d_in[20];

  const size_t MB = 1ull << 20;
  if (ws_size < 142 * MB) return;  // fail loudly (validation will catch it)

  uint8_t* ws = (uint8_t*)d_ws;
  // wbuf: [0,64MB). Layer weights use [0,24MB); bf16-Wf (62.5MB) only after
  // the layer loop. qrw overlaps [24MB,88MB) — dead before Wf conversion.
  bf16*  wbuf   = (bf16*)(ws);
  bf16*  wqkv_b = wbuf;                         // 3 x [1024,1024] = 6MB
  bf16*  wo_b   = wbuf + 3u * 1024 * 1024;      // 2MB
  bf16*  w1_b   = wbuf + 4u * 1024 * 1024;      // 8MB
  bf16*  w2_b   = wbuf + 8u * 1024 * 1024;      // 8MB  (ends at 24MB)
  bf16*  qrw    = (bf16*)(ws + 24 * MB);        // QR table [B*H,S,S] = 64MB
  bf16*  relb   = (bf16*)(ws + 88 * MB);        // 256KB
  float* bqkv   = (float*)(ws + 88 * MB + 512 * 1024);  // 12KB
  float* xf     = (float*)(ws + 89 * MB);       // residual f32 [TOK,D] 8MB
  bf16*  xb     = (bf16*)(ws + 97 * MB);        // bf16 x, 4MB
  bf16*  qkvb   = (bf16*)(ws + 101 * MB);       // q|k|v [3][B*H,S,DH] 12MB
  bf16*  qb     = qkvb;
  bf16*  kb     = qkvb + 1u * 32 * 1024 * 64;
  bf16*  vb     = qkvb + 2u * 32 * 1024 * 64;
  bf16*  ob     = (bf16*)(ws + 113 * MB);       // attn out [B,S,D] 4MB
  float* tf     = (float*)(ws + 117 * MB);      // pre-LN GEMM out f32 8MB
  bf16*  hb     = (bf16*)(ws + 125 * MB);       // ffn hidden bf16 16MB (->141)

  embed_k<<<TOK_, 256, 0, stream>>>(tgt, emb, xf, xb);

  for (int l = 0; l < L_; ++l) {
    cvt_small<<<2124, 256, 0, stream>>>(
        Wq + (size_t)l * D_ * D_, Wk + (size_t)l * D_ * D_,
        Wv + (size_t)l * D_ * D_, Wo + (size_t)l * D_ * D_,
        bq + l * D_, bk + l * D_, bv + l * D_,
        rel + (size_t)l * (2 * MAXLEN_ - 1) * DH_,
        wqkv_b, wo_b, bqkv, relb);
    cvt_bf16<<<2048, 256, 0, stream>>>(W1 + (size_t)l * DFF_ * D_, w1_b, DFF_ * D_);
    cvt_bf16<<<2048, 256, 0, stream>>>(W2 + (size_t)l * D_ * DFF_, w2_b, D_ * DFF_);

    // fused Q|K|V projection, N=3072, epilogue scatters to [3][B*H,S,DH]
    gemm_bt<true, false, false, true, true><<<dim3(16, 24, 1), 256, 0, stream>>>(
        xb, wqkv_b, bqkv, nullptr, qkvb, TOK_, 3 * D_, D_, D_, D_, 0, 0, 0, 1.f);

    // QR[bh,i,u] = q'[bh,i,:] . rel[u,:]  (u in [0,1023] suffices, causal)
    gemm_bt<false, false, false, true, false><<<dim3(8, 8, 32), 256, 0, stream>>>(
        qb, relb, nullptr, nullptr, qrw, S_, S_, DH_, DH_, DH_,
        (long long)S_ * DH_, 0, (long long)S_ * S_, 1.f);

    attn_k<<<dim3(16, B_ * H_), 256, 0, stream>>>(qb, kb, vb, qrw, tgt, ob);

    gemm_bt<true, false, true, false, false><<<dim3(16, 8, 1), 256, 0, stream>>>(
        ob, wo_b, bo + l * D_, tf, nullptr, TOK_, D_, D_, D_, D_, 0, 0, 0, 1.f);
    resid_ln<<<TOK_, 256, 0, stream>>>(xf, tf, g1 + l * D_, be1 + l * D_, xf, xb);

    gemm_bt<true, true, false, true, false><<<dim3(16, 32, 1), 256, 0, stream>>>(
        xb, w1_b, b1 + l * DFF_, nullptr, hb, TOK_, DFF_, D_, D_, D_, 0, 0, 0, 1.f);
    gemm_bt<true, false, true, false, false><<<dim3(16, 8, 1), 256, 0, stream>>>(
        hb, w2_b, b2 + l * D_, tf, nullptr, TOK_, D_, DFF_, DFF_, DFF_, 0, 0, 0, 1.f);
    resid_ln<<<TOK_, 256, 0, stream>>>(xf, tf, g2 + l * D_, be2 + l * D_, xf, xb);
  }

  // final vocab projection: [TOK,D] x [V,D]^T -> d_out f32
  cvt_bf16<<<16000, 256, 0, stream>>>(Wf, wbuf, V_ * D_);
  gemm_bt<true, false, true, false, false><<<dim3(16, 250, 1), 256, 0, stream>>>(
      xb, wbuf, bfv, (float*)d_out, nullptr, TOK_, V_, D_, D_, D_, 0, 0, 0, 1.f);
}